// Round 2
// baseline (1232.099 us; speedup 1.0000x reference)
//
#include <hip/hip_runtime.h>
#include <math.h>

#define N_TOK 32768
#define DIM   256
#define KCODE 4096

// ---- workspace layout (float offsets) ----
#define WS_E2      0                      // [4096]
#define WS_COUNTS  4096                   // [4096]
#define WS_LOSSP   8192                   // [256]
#define WS_SCAL    8448                   // [64]  scal[0]=bias
#define WS_CNORM   8512                   // [4096]
#define WS_IDX     12608                  // int [32768]
#define WS_PVAL    45376                  // [32768*4]
#define WS_PIDX    176448                 // int [32768*4]
#define WS_ET      307520                 // eT [4096*256]
#define WS_DWT     1356096                // dwT [4096*256]
// total = 2404672 floats = ~9.2 MB

// ---- output layout (float offsets) ----
#define OUT_Q      0
#define OUT_LOSS   8388608
#define OUT_PERP   8388609
#define OUT_IDX    8388610
#define OUT_EMB    8421378

typedef float v2f __attribute__((ext_vector_type(2)));
typedef float v4f __attribute__((ext_vector_type(4)));

// ||e_k||^2, partials over d with atomics (e2 pre-zeroed)
__global__ void k_e2(const float* __restrict__ emb, float* __restrict__ e2)
{
    int k  = blockIdx.x * 256 + threadIdx.x;
    int d0 = blockIdx.y * 32;
    float s = 0.0f;
#pragma unroll 8
    for (int d = 0; d < 32; ++d) {
        float v = emb[(size_t)(d0 + d) * KCODE + k];
        s += v * v;
    }
    atomicAdd(&e2[k], s);
}

// embeddings [D][K] -> eT [K][D]
__global__ void k_transpose(const float* __restrict__ emb, float* __restrict__ eT)
{
    __shared__ float tile[32][33];
    int t  = threadIdx.x;
    int tx = t & 31, iy = t >> 5;
    int k0 = blockIdx.x * 32, d0 = blockIdx.y * 32;
#pragma unroll
    for (int j = 0; j < 4; ++j)
        tile[iy + 8 * j][tx] = emb[(size_t)(d0 + iy + 8 * j) * KCODE + k0 + tx];
    __syncthreads();
#pragma unroll
    for (int j = 0; j < 4; ++j)
        eT[(size_t)(k0 + iy + 8 * j) * DIM + d0 + tx] = tile[tx][iy + 8 * j];
}

// x [N][D] -> xT [D][N]  (xT lives in the d_out quantized region until k_gather)
__global__ void k_transpose_x(const float* __restrict__ x, float* __restrict__ xT)
{
    __shared__ float tile[32][33];
    int t  = threadIdx.x;
    int tx = t & 31, iy = t >> 5;
    int n0 = blockIdx.x * 32, d0 = blockIdx.y * 32;
#pragma unroll
    for (int j = 0; j < 4; ++j)
        tile[iy + 8 * j][tx] = x[(size_t)(n0 + iy + 8 * j) * DIM + d0 + tx];
    __syncthreads();
#pragma unroll
    for (int j = 0; j < 4; ++j)
        xT[(size_t)(d0 + iy + 8 * j) * N_TOK + n0 + tx] = tile[tx][iy + 8 * j];
}

// Distance argmin, split-K. Block: 128 rows x 1024-code slice.
// A fragments read straight from global xT (L1-broadcast); only B tile in LDS.
__global__ __launch_bounds__(256, 4)
void k_argmin(const float* __restrict__ xT, const float* __restrict__ emb,
              const float* __restrict__ e2, float* __restrict__ pval,
              int* __restrict__ pidx)
{
    __shared__ __align__(16) float Bs[32][140];   // [d][code], swizzled +4 per 32
    __shared__ __align__(16) float e2s[128];

    const int t  = threadIdx.x;
    const int tx = t & 15, ty = t >> 4;
    const int row0  = blockIdx.x * 128;
    const int kbase = blockIdx.y * 1024;

    float best[8];
    int   bidx[8];
#pragma unroll
    for (int i = 0; i < 8; ++i) { best[i] = 3.4e38f; bidx[i] = 0; }

    const int lb_d  = t >> 3;  // B stage: d row 0..31
    const int lb_c8 = t & 7;   // B stage: float4 col group

    const float* xbase = xT + row0 + ty * 8;

    for (int kc = 0; kc < 1024; kc += 128) {
        const int k0 = kbase + kc;
        v2f acc[8][4];
#pragma unroll
        for (int i = 0; i < 8; ++i)
#pragma unroll
            for (int c = 0; c < 4; ++c) { acc[i][c].x = 0.0f; acc[i][c].y = 0.0f; }

        for (int dc = 0; dc < 256; dc += 32) {
            __syncthreads();
            // stage B: emb[dc..dc+31][k0..k0+127] -> Bs[d][cmap(c)]
#pragma unroll
            for (int j = 0; j < 4; ++j) {
                int c = lb_c8 * 4 + 32 * j;
                float4 v = *(const float4*)&emb[(size_t)(dc + lb_d) * KCODE + k0 + c];
                *(float4*)&Bs[lb_d][c + 4 * (c >> 5)] = v;
            }
            if (dc == 0 && t < 32)
                *(float4*)&e2s[t * 4] = *(const float4*)&e2[k0 + t * 4];
            __syncthreads();

            const float* xp = xbase + (size_t)dc * N_TOK;
#pragma unroll 8
            for (int d = 0; d < 32; ++d) {
                v4f a0 = *(const v4f*)(xp);
                v4f a1 = *(const v4f*)(xp + 4);
                xp += N_TOK;
                const float* bp = &Bs[d][tx * 8 + ((tx >> 2) << 2)];
                v4f b0 = *(const v4f*)bp;
                v4f b1 = *(const v4f*)(bp + 4);
                v2f bv[4];
                bv[0] = __builtin_shufflevector(b0, b0, 0, 1);
                bv[1] = __builtin_shufflevector(b0, b0, 2, 3);
                bv[2] = __builtin_shufflevector(b1, b1, 0, 1);
                bv[3] = __builtin_shufflevector(b1, b1, 2, 3);
                float a[8];
                a[0] = a0.x; a[1] = a0.y; a[2] = a0.z; a[3] = a0.w;
                a[4] = a1.x; a[5] = a1.y; a[6] = a1.z; a[7] = a1.w;
#pragma unroll
                for (int i = 0; i < 8; ++i) {
                    v2f as; as.x = a[i]; as.y = a[i];
#pragma unroll
                    for (int c = 0; c < 4; ++c)
                        acc[i][c] += as * bv[c];   // v_pk_fma_f32
                }
            }
        }
        // fold into running argmin (codes ascending => strict < keeps lowest idx)
#pragma unroll
        for (int i = 0; i < 8; ++i) {
#pragma unroll
            for (int c = 0; c < 4; ++c) {
                int kk = k0 + tx * 8 + c * 2;
                float v0 = e2s[tx * 8 + c * 2]     - 2.0f * acc[i][c].x;
                float v1 = e2s[tx * 8 + c * 2 + 1] - 2.0f * acc[i][c].y;
                if (v0 < best[i]) { best[i] = v0; bidx[i] = kk; }
                if (v1 < best[i]) { best[i] = v1; bidx[i] = kk + 1; }
            }
        }
    }

    // block reduction across the 16 tx threads per row (reuse Bs as scratch)
    __syncthreads();
    float* vals = &Bs[0][0];              // 2048 floats
    int*   idxs = (int*)(&Bs[0][0] + 2048);
#pragma unroll
    for (int i = 0; i < 8; ++i) {
        int r = ty * 8 + i;
        vals[r * 16 + tx] = best[i];
        idxs[r * 16 + tx] = bidx[i];
    }
    __syncthreads();
    if (t < 128) {
        float bv = vals[t * 16];
        int   bi = idxs[t * 16];
#pragma unroll
        for (int j = 1; j < 16; ++j) {
            float v = vals[t * 16 + j];
            int  ii = idxs[t * 16 + j];
            if (v < bv || (v == bv && ii < bi)) { bv = v; bi = ii; }
        }
        pval[(size_t)(row0 + t) * 4 + blockIdx.y] = bv;
        pidx[(size_t)(row0 + t) * 4 + blockIdx.y] = bi;
    }
}

__global__ void k_merge(const float* __restrict__ pval, const int* __restrict__ pidx,
                        int* __restrict__ idx_out)
{
    int n = blockIdx.x * 256 + threadIdx.x;
    float bv = pval[(size_t)n * 4];
    int   bi = pidx[(size_t)n * 4];
#pragma unroll
    for (int s = 1; s < 4; ++s) {
        float v = pval[(size_t)n * 4 + s];
        int  ii = pidx[(size_t)n * 4 + s];
        if (v < bv || (v == bv && ii < bi)) { bv = v; bi = ii; }
    }
    idx_out[n] = bi;
}

// one wave per row: quantized copy, (q-x)^2 loss, counts, dwT scatter, idx float
__global__ void k_gather(const float* __restrict__ x, const float* __restrict__ eT,
                         const int* __restrict__ idx, float* __restrict__ out_q,
                         float* __restrict__ out_idxf, float* __restrict__ counts,
                         float* __restrict__ dwT, float* __restrict__ lossp)
{
    int t = threadIdx.x;
    int lane = t & 63, w = t >> 6;
    int n = blockIdx.x * 4 + w;
    int k = idx[n];
    float4 xv = *(const float4*)&x[(size_t)n * DIM + lane * 4];
    float4 ev = *(const float4*)&eT[(size_t)k * DIM + lane * 4];
    *(float4*)&out_q[(size_t)n * DIM + lane * 4] = ev;
    float dx = ev.x - xv.x, dy = ev.y - xv.y, dz = ev.z - xv.z, dw = ev.w - xv.w;
    float s = dx * dx + dy * dy + dz * dz + dw * dw;
#pragma unroll
    for (int off = 32; off > 0; off >>= 1) s += __shfl_down(s, off, 64);
    float* dp = &dwT[(size_t)k * DIM + lane * 4];
    atomicAdd(dp + 0, xv.x);
    atomicAdd(dp + 1, xv.y);
    atomicAdd(dp + 2, xv.z);
    atomicAdd(dp + 3, xv.w);
    if (lane == 0) {
        atomicAdd(&counts[k], 1.0f);
        atomicAdd(&lossp[blockIdx.x & 255], s);
        out_idxf[n] = (float)k;
    }
}

__global__ void k_finalize(const float* __restrict__ counts, const float* __restrict__ lossp,
                           const float* __restrict__ ema_counter,
                           const float* __restrict__ ema_cluster,
                           float* __restrict__ cnorm, float* __restrict__ scal,
                           float* __restrict__ out)
{
    __shared__ float red[256];
    int t = threadIdx.x;
    float ls = lossp[t];
    float ent = 0.0f, casum = 0.0f;
    float ca[16];
#pragma unroll
    for (int j = 0; j < 16; ++j) {
        int k = j * 256 + t;
        float c = counts[k];
        float p = c * (1.0f / 32768.0f);
        ent += p * logf(p + 1e-10f);
        ca[j] = ema_cluster[k] * 0.99f + c * 0.01f;   // cluster_hidden
        casum += ca[j];
    }
    red[t] = ls; __syncthreads();
    for (int o = 128; o > 0; o >>= 1) { if (t < o) red[t] += red[t + o]; __syncthreads(); }
    float loss_tot = red[0]; __syncthreads();
    red[t] = ent; __syncthreads();
    for (int o = 128; o > 0; o >>= 1) { if (t < o) red[t] += red[t + o]; __syncthreads(); }
    float ent_tot = red[0]; __syncthreads();
    red[t] = casum; __syncthreads();
    for (int o = 128; o > 0; o >>= 1) { if (t < o) red[t] += red[t + o]; __syncthreads(); }
    float casum_tot = red[0]; __syncthreads();

    float bias = 1.0f - powf(0.99f, ema_counter[0] + 1.0f);
    float n = casum_tot / bias;                 // sum(cluster_avg)
    float inv = n / (n + 4096.0f * 1e-5f);
#pragma unroll
    for (int j = 0; j < 16; ++j) {
        int k = j * 256 + t;
        cnorm[k] = (ca[j] / bias + 1e-5f) * inv;
    }
    if (t == 0) {
        out[OUT_LOSS] = 1.25f * loss_tot * (1.0f / (32768.0f * 256.0f));
        out[OUT_PERP] = expf(-ent_tot);
        scal[0] = bias;
    }
}

// new_embeddings[d][k] = (ema_dw*DECAY + dwT^T*(1-DECAY))/bias / cnorm[k]
__global__ void k_newemb(const float* __restrict__ dwT, const float* __restrict__ ema_dw,
                         const float* __restrict__ cnorm, const float* __restrict__ scal,
                         float* __restrict__ out_emb)
{
    __shared__ float tile[32][33];
    int t = threadIdx.x;
    int tx = t & 31, iy = t >> 5;
    int k0 = blockIdx.x * 32, d0 = blockIdx.y * 32;
#pragma unroll
    for (int j = 0; j < 4; ++j)
        tile[iy + 8 * j][tx] = dwT[(size_t)(k0 + iy + 8 * j) * DIM + d0 + tx];
    __syncthreads();
    float inv_bias = 1.0f / scal[0];
    float cn = cnorm[k0 + tx];
#pragma unroll
    for (int j = 0; j < 4; ++j) {
        int d = d0 + iy + 8 * j;
        float dwv = tile[tx][iy + 8 * j];
        float hid = ema_dw[(size_t)d * KCODE + k0 + tx] * 0.99f + dwv * 0.01f;
        out_emb[(size_t)d * KCODE + k0 + tx] = hid * inv_bias / cn;
    }
}

extern "C" void kernel_launch(void* const* d_in, const int* in_sizes, int n_in,
                              void* d_out, int out_size, void* d_ws, size_t ws_size,
                              hipStream_t stream)
{
    const float* x           = (const float*)d_in[0];
    const float* emb         = (const float*)d_in[1];
    const float* ema_counter = (const float*)d_in[2];
    const float* ema_cluster = (const float*)d_in[3];
    const float* ema_dw      = (const float*)d_in[4];
    float* out = (float*)d_out;
    float* ws  = (float*)d_ws;

    float* e2     = ws + WS_E2;
    float* counts = ws + WS_COUNTS;
    float* lossp  = ws + WS_LOSSP;
    float* scal   = ws + WS_SCAL;
    float* cnorm  = ws + WS_CNORM;
    int*   idxw   = (int*)(ws + WS_IDX);
    float* pval   = ws + WS_PVAL;
    int*   pidx   = (int*)(ws + WS_PIDX);
    float* eT     = ws + WS_ET;
    float* dwT    = ws + WS_DWT;
    float* xT     = out + OUT_Q;   // temporary: overwritten later by k_gather

    // zero: e2 + counts + loss partials + scalars, and dwT accumulator
    hipMemsetAsync(e2, 0, (size_t)WS_CNORM * sizeof(float), stream);
    hipMemsetAsync(dwT, 0, (size_t)KCODE * DIM * sizeof(float), stream);

    k_e2<<<dim3(16, 8), 256, 0, stream>>>(emb, e2);
    k_transpose<<<dim3(128, 8), 256, 0, stream>>>(emb, eT);
    k_transpose_x<<<dim3(1024, 8), 256, 0, stream>>>(x, xT);
    k_argmin<<<dim3(256, 4), 256, 0, stream>>>(xT, emb, e2, pval, pidx);
    k_merge<<<128, 256, 0, stream>>>(pval, pidx, idxw);
    k_gather<<<8192, 256, 0, stream>>>(x, eT, idxw, out + OUT_Q, out + OUT_IDX,
                                       counts, dwT, lossp);
    k_finalize<<<1, 256, 0, stream>>>(counts, lossp, ema_counter, ema_cluster,
                                      cnorm, scal, out);
    k_newemb<<<dim3(128, 8), 256, 0, stream>>>(dwT, ema_dw, cnorm, scal, out + OUT_EMB);
}

// Round 3
// 710.234 us; speedup vs baseline: 1.7348x; 1.7348x over previous
//
#include <hip/hip_runtime.h>
#include <math.h>

#define N_TOK 32768
#define DIM   256
#define KCODE 4096

// ---- workspace layout (float offsets) ----
#define WS_E2      0                      // [4096]
#define WS_COUNTS  4096                   // [4096]
#define WS_LOSSP   8192                   // [256]
#define WS_SCAL    8448                   // [64]  scal[0]=bias
#define WS_CNORM   8512                   // [4096]
#define WS_IDX     12608                  // int [32768]
#define WS_ET      307520                 // eT [4096*256]
#define WS_DWT     1356096                // dwT [4096*256]

// ---- output layout (float offsets) ----
#define OUT_Q      0
#define OUT_LOSS   8388608
#define OUT_PERP   8388609
#define OUT_IDX    8388610
#define OUT_EMB    8421378

typedef _Float16 f16x8 __attribute__((ext_vector_type(8)));
typedef float    f32x4 __attribute__((ext_vector_type(4)));

// ||e_k||^2, partials over d with atomics (e2 pre-zeroed)
__global__ void k_e2(const float* __restrict__ emb, float* __restrict__ e2)
{
    int k  = blockIdx.x * 256 + threadIdx.x;
    int d0 = blockIdx.y * 32;
    float s = 0.0f;
#pragma unroll 8
    for (int d = 0; d < 32; ++d) {
        float v = emb[(size_t)(d0 + d) * KCODE + k];
        s += v * v;
    }
    atomicAdd(&e2[k], s);
}

// embeddings [D][K] -> eT [K][D]
__global__ void k_transpose(const float* __restrict__ emb, float* __restrict__ eT)
{
    __shared__ float tile[32][33];
    int t  = threadIdx.x;
    int tx = t & 31, iy = t >> 5;
    int k0 = blockIdx.x * 32, d0 = blockIdx.y * 32;
#pragma unroll
    for (int j = 0; j < 4; ++j)
        tile[iy + 8 * j][tx] = emb[(size_t)(d0 + iy + 8 * j) * KCODE + k0 + tx];
    __syncthreads();
#pragma unroll
    for (int j = 0; j < 4; ++j)
        eT[(size_t)(k0 + iy + 8 * j) * DIM + d0 + tx] = tile[tx][iy + 8 * j];
}

// Argmin over codes via fp16x2-split MFMA.
// Block: 32 rows, scans all 4096 codes in 32 tiles of 128 (wave w owns 32 codes).
__global__ __launch_bounds__(256, 3)
void k_argmin(const float* __restrict__ x, const float* __restrict__ eT,
              const float* __restrict__ e2, int* __restrict__ idx_out)
{
    __shared__ __align__(16) _Float16 Ah[2][32][256];  // split planes of x-tile, XOR-swizzled 8-elem groups
    __shared__ __align__(16) _Float16 Bh[2][128][40];  // split planes of code k-slice (32 k + 8 pad)
    __shared__ float e2s[128];

    const int t    = threadIdx.x;
    const int lane = t & 63, w = t >> 6;
    const int lo   = lane & 15, q = lane >> 4;
    const int row0 = blockIdx.x * 32;

    // ---- prologue: stage A = x[row0..+32][0..256] into split fp16 planes ----
    {
        int m = t >> 3, kb = (t & 7) * 32;      // 32 k per thread
        const float* src = &x[(size_t)(row0 + m) * DIM + kb];
#pragma unroll
        for (int g = 0; g < 4; ++g) {           // 4 groups of 8
            float4 f0 = *(const float4*)(src + g * 8);
            float4 f1 = *(const float4*)(src + g * 8 + 4);
            float fv[8] = {f0.x, f0.y, f0.z, f0.w, f1.x, f1.y, f1.z, f1.w};
            f16x8 h1, h2;
#pragma unroll
            for (int j = 0; j < 8; ++j) {
                _Float16 a = (_Float16)fv[j];
                h1[j] = a;
                h2[j] = (_Float16)(fv[j] - (float)a);
            }
            int grp = ((kb >> 3) + g) ^ (m & 7);
            *(f16x8*)&Ah[0][m][grp * 8] = h1;
            *(f16x8*)&Ah[1][m][grp * 8] = h2;
        }
    }

    float best[8];
    int   bidx[8];
#pragma unroll
    for (int s = 0; s < 8; ++s) { best[s] = 3.4e38f; bidx[s] = 0; }

    // B staging assignment: thread -> (code row, k-half)
    const int bn  = t >> 1;          // 0..127
    const int bkh = (t & 1) * 16;    // 0 or 16

    // prefetch first B slice (ct=0, ks=0)
    float4 pf[4];
    {
        const float* bsrc = &eT[(size_t)bn * DIM + bkh];
#pragma unroll
        for (int j = 0; j < 4; ++j) pf[j] = *(const float4*)(bsrc + j * 4);
    }

    const int aswz = (lo & 7);

    for (int ct = 0; ct < 32; ++ct) {
        f32x4 acc[2][2];
#pragma unroll
        for (int mf = 0; mf < 2; ++mf)
#pragma unroll
            for (int nf = 0; nf < 2; ++nf) acc[mf][nf] = (f32x4)0.0f;

        for (int ks = 0; ks < 8; ++ks) {
            // convert prefetched 16 floats -> split halves
            float fv[16];
#pragma unroll
            for (int j = 0; j < 4; ++j) {
                fv[j * 4 + 0] = pf[j].x; fv[j * 4 + 1] = pf[j].y;
                fv[j * 4 + 2] = pf[j].z; fv[j * 4 + 3] = pf[j].w;
            }
            f16x8 h1a, h1b, h2a, h2b;
#pragma unroll
            for (int j = 0; j < 8; ++j) {
                _Float16 a = (_Float16)fv[j];
                h1a[j] = a; h2a[j] = (_Float16)(fv[j] - (float)a);
                _Float16 b = (_Float16)fv[j + 8];
                h1b[j] = b; h2b[j] = (_Float16)(fv[j + 8] - (float)b);
            }
            __syncthreads();   // all waves done reading Bh/e2s of previous slice
            *(f16x8*)&Bh[0][bn][bkh + 0] = h1a;
            *(f16x8*)&Bh[0][bn][bkh + 8] = h1b;
            *(f16x8*)&Bh[1][bn][bkh + 0] = h2a;
            *(f16x8*)&Bh[1][bn][bkh + 8] = h2b;
            if (ks == 0 && t < 32)
                *(float4*)&e2s[t * 4] = *(const float4*)&e2[ct * 128 + t * 4];
            __syncthreads();

            // prefetch next slice while computing
            int nit = ct * 8 + ks + 1;
            if (nit < 256) {
                int nct = nit >> 3, nks = nit & 7;
                const float* bsrc = &eT[(size_t)(nct * 128 + bn) * DIM + nks * 32 + bkh];
#pragma unroll
                for (int j = 0; j < 4; ++j) pf[j] = *(const float4*)(bsrc + j * 4);
            }

            // fragments
            int agrp = ((ks * 4 + q) ^ aswz) * 8;
            f16x8 a1_0 = *(const f16x8*)&Ah[0][lo][agrp];
            f16x8 a2_0 = *(const f16x8*)&Ah[1][lo][agrp];
            f16x8 a1_1 = *(const f16x8*)&Ah[0][lo + 16][agrp];
            f16x8 a2_1 = *(const f16x8*)&Ah[1][lo + 16][agrp];
            f16x8 b1_0 = *(const f16x8*)&Bh[0][w * 32 + lo][q * 8];
            f16x8 b2_0 = *(const f16x8*)&Bh[1][w * 32 + lo][q * 8];
            f16x8 b1_1 = *(const f16x8*)&Bh[0][w * 32 + 16 + lo][q * 8];
            f16x8 b2_1 = *(const f16x8*)&Bh[1][w * 32 + 16 + lo][q * 8];

            acc[0][0] = __builtin_amdgcn_mfma_f32_16x16x32_f16(a2_0, b1_0, acc[0][0], 0, 0, 0);
            acc[0][1] = __builtin_amdgcn_mfma_f32_16x16x32_f16(a2_0, b1_1, acc[0][1], 0, 0, 0);
            acc[1][0] = __builtin_amdgcn_mfma_f32_16x16x32_f16(a2_1, b1_0, acc[1][0], 0, 0, 0);
            acc[1][1] = __builtin_amdgcn_mfma_f32_16x16x32_f16(a2_1, b1_1, acc[1][1], 0, 0, 0);
            acc[0][0] = __builtin_amdgcn_mfma_f32_16x16x32_f16(a1_0, b2_0, acc[0][0], 0, 0, 0);
            acc[0][1] = __builtin_amdgcn_mfma_f32_16x16x32_f16(a1_0, b2_1, acc[0][1], 0, 0, 0);
            acc[1][0] = __builtin_amdgcn_mfma_f32_16x16x32_f16(a1_1, b2_0, acc[1][0], 0, 0, 0);
            acc[1][1] = __builtin_amdgcn_mfma_f32_16x16x32_f16(a1_1, b2_1, acc[1][1], 0, 0, 0);
            acc[0][0] = __builtin_amdgcn_mfma_f32_16x16x32_f16(a1_0, b1_0, acc[0][0], 0, 0, 0);
            acc[0][1] = __builtin_amdgcn_mfma_f32_16x16x32_f16(a1_0, b1_1, acc[0][1], 0, 0, 0);
            acc[1][0] = __builtin_amdgcn_mfma_f32_16x16x32_f16(a1_1, b1_0, acc[1][0], 0, 0, 0);
            acc[1][1] = __builtin_amdgcn_mfma_f32_16x16x32_f16(a1_1, b1_1, acc[1][1], 0, 0, 0);
        }

        // fold: dist = e2 - 2*score  (x^2 row-constant dropped). codes ascending.
#pragma unroll
        for (int mf = 0; mf < 2; ++mf)
#pragma unroll
            for (int nf = 0; nf < 2; ++nf)
#pragma unroll
                for (int r = 0; r < 4; ++r) {
                    int cl = w * 32 + nf * 16 + lo;
                    float dist = fmaf(-2.0f, acc[mf][nf][r], e2s[cl]);
                    int s = mf * 4 + r;
                    if (dist < best[s]) { best[s] = dist; bidx[s] = ct * 128 + cl; }
                }
    }

    // ---- final argmin reduction across lanes (scratch overlays Ah) ----
    __syncthreads();
    float* rv = (float*)&Ah[0][0][0];
    int*   ri = (int*)(((char*)&Ah[0][0][0]) + 8192);
#pragma unroll
    for (int s = 0; s < 8; ++s) {
        int row = (s >> 2) * 16 + q * 4 + (s & 3);
        rv[row * 64 + w * 16 + lo] = best[s];
        ri[row * 64 + w * 16 + lo] = bidx[s];
    }
    __syncthreads();
    if (t < 32) {
        float bv = rv[t * 64];
        int   bi = ri[t * 64];
        for (int j = 1; j < 64; ++j) {
            float v = rv[t * 64 + j];
            int  ii = ri[t * 64 + j];
            if (v < bv || (v == bv && ii < bi)) { bv = v; bi = ii; }
        }
        idx_out[row0 + t] = bi;
    }
}

// one wave per row: quantized copy, (q-x)^2 loss, counts, dwT scatter, idx float
__global__ void k_gather(const float* __restrict__ x, const float* __restrict__ eT,
                         const int* __restrict__ idx, float* __restrict__ out_q,
                         float* __restrict__ out_idxf, float* __restrict__ counts,
                         float* __restrict__ dwT, float* __restrict__ lossp)
{
    int t = threadIdx.x;
    int lane = t & 63, w = t >> 6;
    int n = blockIdx.x * 4 + w;
    int k = idx[n];
    float4 xv = *(const float4*)&x[(size_t)n * DIM + lane * 4];
    float4 ev = *(const float4*)&eT[(size_t)k * DIM + lane * 4];
    *(float4*)&out_q[(size_t)n * DIM + lane * 4] = ev;
    float dx = ev.x - xv.x, dy = ev.y - xv.y, dz = ev.z - xv.z, dw = ev.w - xv.w;
    float s = dx * dx + dy * dy + dz * dz + dw * dw;
#pragma unroll
    for (int off = 32; off > 0; off >>= 1) s += __shfl_down(s, off, 64);
    float* dp = &dwT[(size_t)k * DIM + lane * 4];
    atomicAdd(dp + 0, xv.x);
    atomicAdd(dp + 1, xv.y);
    atomicAdd(dp + 2, xv.z);
    atomicAdd(dp + 3, xv.w);
    if (lane == 0) {
        atomicAdd(&counts[k], 1.0f);
        atomicAdd(&lossp[blockIdx.x & 255], s);
        out_idxf[n] = (float)k;
    }
}

__global__ void k_finalize(const float* __restrict__ counts, const float* __restrict__ lossp,
                           const float* __restrict__ ema_counter,
                           const float* __restrict__ ema_cluster,
                           float* __restrict__ cnorm, float* __restrict__ scal,
                           float* __restrict__ out)
{
    __shared__ float red[256];
    int t = threadIdx.x;
    float ls = lossp[t];
    float ent = 0.0f, casum = 0.0f;
    float ca[16];
#pragma unroll
    for (int j = 0; j < 16; ++j) {
        int k = j * 256 + t;
        float c = counts[k];
        float p = c * (1.0f / 32768.0f);
        ent += p * logf(p + 1e-10f);
        ca[j] = ema_cluster[k] * 0.99f + c * 0.01f;   // cluster_hidden
        casum += ca[j];
    }
    red[t] = ls; __syncthreads();
    for (int o = 128; o > 0; o >>= 1) { if (t < o) red[t] += red[t + o]; __syncthreads(); }
    float loss_tot = red[0]; __syncthreads();
    red[t] = ent; __syncthreads();
    for (int o = 128; o > 0; o >>= 1) { if (t < o) red[t] += red[t + o]; __syncthreads(); }
    float ent_tot = red[0]; __syncthreads();
    red[t] = casum; __syncthreads();
    for (int o = 128; o > 0; o >>= 1) { if (t < o) red[t] += red[t + o]; __syncthreads(); }
    float casum_tot = red[0]; __syncthreads();

    float bias = 1.0f - powf(0.99f, ema_counter[0] + 1.0f);
    float n = casum_tot / bias;                 // sum(cluster_avg)
    float inv = n / (n + 4096.0f * 1e-5f);
#pragma unroll
    for (int j = 0; j < 16; ++j) {
        int k = j * 256 + t;
        cnorm[k] = (ca[j] / bias + 1e-5f) * inv;
    }
    if (t == 0) {
        out[OUT_LOSS] = 1.25f * loss_tot * (1.0f / (32768.0f * 256.0f));
        out[OUT_PERP] = expf(-ent_tot);
        scal[0] = bias;
    }
}

// new_embeddings[d][k] = (ema_dw*DECAY + dwT^T*(1-DECAY))/bias / cnorm[k]
__global__ void k_newemb(const float* __restrict__ dwT, const float* __restrict__ ema_dw,
                         const float* __restrict__ cnorm, const float* __restrict__ scal,
                         float* __restrict__ out_emb)
{
    __shared__ float tile[32][33];
    int t = threadIdx.x;
    int tx = t & 31, iy = t >> 5;
    int k0 = blockIdx.x * 32, d0 = blockIdx.y * 32;
#pragma unroll
    for (int j = 0; j < 4; ++j)
        tile[iy + 8 * j][tx] = dwT[(size_t)(k0 + iy + 8 * j) * DIM + d0 + tx];
    __syncthreads();
    float inv_bias = 1.0f / scal[0];
    float cn = cnorm[k0 + tx];
#pragma unroll
    for (int j = 0; j < 4; ++j) {
        int d = d0 + iy + 8 * j;
        float dwv = tile[tx][iy + 8 * j];
        float hid = ema_dw[(size_t)d * KCODE + k0 + tx] * 0.99f + dwv * 0.01f;
        out_emb[(size_t)d * KCODE + k0 + tx] = hid * inv_bias / cn;
    }
}

extern "C" void kernel_launch(void* const* d_in, const int* in_sizes, int n_in,
                              void* d_out, int out_size, void* d_ws, size_t ws_size,
                              hipStream_t stream)
{
    const float* x           = (const float*)d_in[0];
    const float* emb         = (const float*)d_in[1];
    const float* ema_counter = (const float*)d_in[2];
    const float* ema_cluster = (const float*)d_in[3];
    const float* ema_dw      = (const float*)d_in[4];
    float* out = (float*)d_out;
    float* ws  = (float*)d_ws;

    float* e2     = ws + WS_E2;
    float* counts = ws + WS_COUNTS;
    float* lossp  = ws + WS_LOSSP;
    float* scal   = ws + WS_SCAL;
    float* cnorm  = ws + WS_CNORM;
    int*   idxw   = (int*)(ws + WS_IDX);
    float* eT     = ws + WS_ET;
    float* dwT    = ws + WS_DWT;

    // zero: e2 + counts + loss partials + scalars, and dwT accumulator
    hipMemsetAsync(e2, 0, (size_t)WS_CNORM * sizeof(float), stream);
    hipMemsetAsync(dwT, 0, (size_t)KCODE * DIM * sizeof(float), stream);

    k_e2<<<dim3(16, 8), 256, 0, stream>>>(emb, e2);
    k_transpose<<<dim3(128, 8), 256, 0, stream>>>(emb, eT);
    k_argmin<<<1024, 256, 0, stream>>>(x, eT, e2, idxw);
    k_gather<<<8192, 256, 0, stream>>>(x, eT, idxw, out + OUT_Q, out + OUT_IDX,
                                       counts, dwT, lossp);
    k_finalize<<<1, 256, 0, stream>>>(counts, lossp, ema_counter, ema_cluster,
                                      cnorm, scal, out);
    k_newemb<<<dim3(128, 8), 256, 0, stream>>>(dwT, ema_dw, cnorm, scal, out + OUT_EMB);
}